// Round 1
// baseline (944.800 us; speedup 1.0000x reference)
//
#include <hip/hip_runtime.h>

// Junction tree dims
#define D0   256
#define D1F  1024
#define D1C  256
#define D2   256
#define D3F  512
#define D3C  256
#define D4   512

// workspace layout (float offsets). Total 524288 floats = 2 MB.
#define OFF_MSG01 0        // 256*256   (atomic-accumulated; zeroed)
#define OFF_S10   65536    // 256*512   (atomic-accumulated; zeroed)
#define OFF_S12   196608   // 256*256   (direct store)
#define OFF_S22   262144   // 256*256   (direct store)
#define OFF_MSG12 327680   // 256*256
#define OFF_S2    393216   // 256*256
#define OFF_S3    458752   // 256*256

// ---------------------------------------------------------------------------
// R0: msg01[f,c] = sum_{i<256, j in [4f,4f+4)} theta0[i,j,c]
// grid (f=256, ichunk=16), block 256. Wave w reads row j=4f+w (64 float4s,
// perfectly coalesced), loops over 16 i's; LDS-reduce across the 4 waves,
// then 16-way atomicAdd into msg01.
__global__ __launch_bounds__(256) void k_r0(const float* __restrict__ t0,
                                            float* __restrict__ ws) {
  float* msg01 = ws + OFF_MSG01;
  const int f = blockIdx.x, ic = blockIdx.y, t = threadIdx.x;
  const int c4 = t & 63, r = t >> 6;
  const float4* t0v = (const float4*)t0;
  const int j = 4 * f + r;
  float4 acc = make_float4(0.f, 0.f, 0.f, 0.f);
#pragma unroll
  for (int it = 0; it < 16; ++it) {
    const int i = ic * 16 + it;
    float4 v = t0v[((size_t)i * D1F + j) * 64 + c4];
    acc.x += v.x; acc.y += v.y; acc.z += v.z; acc.w += v.w;
  }
  __shared__ float4 lds[256];
  lds[t] = acc;
  __syncthreads();
  if (t < 64) {
    float4 a0 = lds[t], a1 = lds[t + 64], a2 = lds[t + 128], a3 = lds[t + 192];
    float* dst = &msg01[f * D2 + 4 * t];
    atomicAdd(dst + 0, a0.x + a1.x + a2.x + a3.x);
    atomicAdd(dst + 1, a0.y + a1.y + a2.y + a3.y);
    atomicAdd(dst + 2, a0.z + a1.z + a2.z + a3.z);
    atomicAdd(dst + 3, a0.w + a1.w + a2.w + a3.w);
  }
}

// ---------------------------------------------------------------------------
// R1: single read of theta1 producing both
//   S10[c,k] = sum_a theta1[a,c,k]   (atomic, 16-way)
//   S12[a,c] = sum_k theta1[a,c,k]   (direct store)
// grid (c=256, achunk=16), block 256 (float2 per thread covers the 512-row).
__global__ __launch_bounds__(256) void k_r1(const float* __restrict__ t1,
                                            float* __restrict__ ws) {
  float* S10 = ws + OFF_S10;
  float* S12 = ws + OFF_S12;
  const int c = blockIdx.x, ac = blockIdx.y, t = threadIdx.x;
  const int lane = t & 63, w = t >> 6;
  __shared__ float red[4];
  float sx = 0.f, sy = 0.f;
  for (int aa = 0; aa < 16; ++aa) {
    const int a = ac * 16 + aa;
    const float2* row = (const float2*)(t1 + ((size_t)a * D2 + c) * D3F);
    float2 v = row[t];
    sx += v.x; sy += v.y;
    float p = v.x + v.y;
#pragma unroll
    for (int off = 32; off; off >>= 1) p += __shfl_down(p, off);
    if (lane == 0) red[w] = p;
    __syncthreads();
    if (t == 0) S12[a * D2 + c] = red[0] + red[1] + red[2] + red[3];
    __syncthreads();
  }
  atomicAdd(&S10[c * D3F + 2 * t + 0], sx);
  atomicAdd(&S10[c * D3F + 2 * t + 1], sy);
}

// ---------------------------------------------------------------------------
// tiny1: msg12[c,f] = S10[c,2f] + S10[c,2f+1] + 2*colA[c],
//        colA[c] = sum_a msg01[a,c].   grid 256 (c), block 256 (t=a then t=f)
__global__ __launch_bounds__(256) void k_msg12(float* __restrict__ ws) {
  const float* msg01 = ws + OFF_MSG01;
  const float* S10   = ws + OFF_S10;
  float* msg12       = ws + OFF_MSG12;
  const int c = blockIdx.x, t = threadIdx.x;
  float p = msg01[t * D2 + c];
#pragma unroll
  for (int off = 32; off; off >>= 1) p += __shfl_down(p, off);
  __shared__ float red[4];
  if ((t & 63) == 0) red[t >> 6] = p;
  __syncthreads();
  const float colA = red[0] + red[1] + red[2] + red[3];
  msg12[c * D3C + t] = S10[c * D3F + 2 * t] + S10[c * D3F + 2 * t + 1] + 2.f * colA;
}

// ---------------------------------------------------------------------------
// W2 (+fused R2): theta2_out = theta2 + msg12[c,f] broadcast over k,
// and S22[c,f] = sum_k theta2[c,f,k] in the same read.
// grid (c=256, fchunk=16), block 256 (float2 per thread).
__global__ __launch_bounds__(256) void k_w2(const float* __restrict__ t2,
                                            float* __restrict__ out2,
                                            float* __restrict__ ws) {
  const float* msg12 = ws + OFF_MSG12;
  float* S22         = ws + OFF_S22;
  const int c = blockIdx.x, fc = blockIdx.y, t = threadIdx.x;
  const int lane = t & 63, w = t >> 6;
  __shared__ float red[4];
  for (int ff = 0; ff < 16; ++ff) {
    const int f = fc * 16 + ff;
    const size_t base = ((size_t)c * D3C + f) * D4;
    float2 v = ((const float2*)(t2 + base))[t];
    const float m = msg12[c * D3C + f];
    float2 o; o.x = v.x + m; o.y = v.y + m;
    ((float2*)(out2 + base))[t] = o;
    float p = v.x + v.y;
#pragma unroll
    for (int off = 32; off; off >>= 1) p += __shfl_down(p, off);
    if (lane == 0) red[w] = p;
    __syncthreads();
    if (t == 0) S22[c * D3C + f] = red[0] + red[1] + red[2] + red[3];
    __syncthreads();
  }
}

// ---------------------------------------------------------------------------
// tiny2: s2[c,f] = S22 + 511*msg12 ; s3[a,c] = S12 + 511*msg01 + 2*sum_f s2[c,f]
// grid 256 (c), block 256.
__global__ __launch_bounds__(256) void k_s3(float* __restrict__ ws) {
  const float* msg01 = ws + OFF_MSG01;
  const float* S12   = ws + OFF_S12;
  const float* S22   = ws + OFF_S22;
  const float* msg12 = ws + OFF_MSG12;
  float* s2          = ws + OFF_S2;
  float* s3          = ws + OFF_S3;
  const int c = blockIdx.x, t = threadIdx.x;
  const float m12 = msg12[c * D3C + t];
  const float s2v = S22[c * D3C + t] + 511.f * m12;
  s2[c * D3C + t] = s2v;
  float p = s2v;
#pragma unroll
  for (int off = 32; off; off >>= 1) p += __shfl_down(p, off);
  __shared__ float red[4];
  if ((t & 63) == 0) red[t >> 6] = p;
  __syncthreads();
  const float rs = red[0] + red[1] + red[2] + red[3];
  // t plays 'a' here
  s3[t * D2 + c] = S12[t * D2 + c] + 511.f * msg01[t * D2 + c] + 2.f * rs;
}

// ---------------------------------------------------------------------------
// W1: theta1_out[a,c,k] = theta1 + msg01[a,c] + s2[c, k>>1]. float4 flat.
__global__ __launch_bounds__(256) void k_w1(const float* __restrict__ t1,
                                            float* __restrict__ out1,
                                            const float* __restrict__ ws) {
  const float* msg01 = ws + OFF_MSG01;
  const float* s2    = ws + OFF_S2;
  const size_t idx = (size_t)blockIdx.x * 256 + threadIdx.x;  // float4 index
  const int k4 = (int)(idx & 127);
  const int c  = (int)((idx >> 7) & 255);
  const int a  = (int)(idx >> 15);
  float4 v = ((const float4*)t1)[idx];
  const float m  = msg01[a * D2 + c];
  const float sa = s2[c * D3C + 2 * k4];
  const float sb = s2[c * D3C + 2 * k4 + 1];
  float4 o;
  o.x = v.x + m + sa; o.y = v.y + m + sa;
  o.z = v.z + m + sb; o.w = v.w + m + sb;
  ((float4*)out1)[idx] = o;
}

// ---------------------------------------------------------------------------
// W0: theta0_out[i,j,c] = theta0 + s3[j>>2, c]. float4 flat.
__global__ __launch_bounds__(256) void k_w0(const float* __restrict__ t0,
                                            float* __restrict__ out0,
                                            const float* __restrict__ ws) {
  const float4* s3v = (const float4*)(ws + OFF_S3);
  const size_t idx = (size_t)blockIdx.x * 256 + threadIdx.x;  // float4 index
  const int c4 = (int)(idx & 63);
  const int j  = (int)((idx >> 6) & 1023);
  float4 v = ((const float4*)t0)[idx];
  float4 m = s3v[(j >> 2) * 64 + c4];
  float4 o;
  o.x = v.x + m.x; o.y = v.y + m.y; o.z = v.z + m.z; o.w = v.w + m.w;
  ((float4*)out0)[idx] = o;
}

extern "C" void kernel_launch(void* const* d_in, const int* in_sizes, int n_in,
                              void* d_out, int out_size, void* d_ws, size_t ws_size,
                              hipStream_t stream) {
  const float* t0 = (const float*)d_in[0];
  const float* t1 = (const float*)d_in[1];
  const float* t2 = (const float*)d_in[2];
  // selection matrices d_in[3..6] are structurally known (f = j/4, f = j/2)
  float* out0 = (float*)d_out;
  float* out1 = out0 + (size_t)D0 * D1F * D2;   // 67,108,864
  float* out2 = out1 + (size_t)D1C * D2 * D3F;  // +33,554,432
  float* ws = (float*)d_ws;

  // zero the atomic accumulators (msg01 + S10)
  hipMemsetAsync(d_ws, 0, (size_t)OFF_S12 * sizeof(float), stream);

  k_r0<<<dim3(256, 16), 256, 0, stream>>>(t0, ws);
  k_r1<<<dim3(256, 16), 256, 0, stream>>>(t1, ws);
  k_msg12<<<256, 256, 0, stream>>>(ws);
  k_w2<<<dim3(256, 16), 256, 0, stream>>>(t2, out2, ws);
  k_s3<<<256, 256, 0, stream>>>(ws);
  k_w1<<<32768, 256, 0, stream>>>(t1, out1, ws);
  k_w0<<<65536, 256, 0, stream>>>(t0, out0, ws);
}